// Round 6
// baseline (48.899 us; speedup 1.0000x reference)
//
#include <hip/hip_runtime.h>

#define NIN   784
#define NOUT  512
#define NROWS 785      // NIN + 1 (bias row)
#define NPAD  800      // padded to 32 chunks * 25 (pad rows contribute 0)
#define BATCH 256
#define CHUNK 25
#define LSPAD 33       // 32 batches + 1 pad
#define NZ    32

static constexpr float G_MIN_F  = (float)(1.0 / 983.3);
static constexpr float G_DIFF_F = (float)(1.0 / 281.3 - 1.0 / 983.3);

// device fast transcendental: v_log_f32 (log2), v_exp_f32 (2^x)
__device__ __forceinline__ float dlog2(float v) { return __builtin_amdgcn_logf(v); }
__device__ __forceinline__ float dexp2(float v) { return __builtin_amdgcn_exp2f(v); }

// ws layout:
//   [0]        : 128 float partial maxima
//   [2048]     : kG,C (fallback path only)
//   [4096]     : table, NPAD*NOUT float4  (6.55 MB)
//   [tab end]  : partials, NZ*BATCH*NOUT float (16.78 MB)
#define WS_PM_OFF   0
#define WS_KG_OFF   2048
#define WS_TAB_OFF  4096
#define WS_PART_OFF (WS_TAB_OFF + (size_t)NPAD * NOUT * 16)
#define WS_TOTAL    (WS_PART_OFF + (size_t)NZ * BATCH * NOUT * 4)

// 256-thread-block reduce of the 128 partial maxima (all threads return max)
__device__ __forceinline__ float load_maxw(const float* __restrict__ pm, int tid) {
    float m = pm[tid & 127];
    #pragma unroll
    for (int off = 1; off < 64; off <<= 1)
        m = fmaxf(m, __shfl_xor(m, off, 64));
    __shared__ float sm2[4];
    if ((tid & 63) == 0) sm2[tid >> 6] = m;
    __syncthreads();
    return fmaxf(fmaxf(sm2[0], sm2[1]), fmaxf(sm2[2], sm2[3]));
}

// ---------------------------------------------------------------------------
// Kernel 1: per-block partial max over |weights| (vectorized).
// ---------------------------------------------------------------------------
__global__ __launch_bounds__(256) void mk_max(
    const float* __restrict__ wp, const float* __restrict__ wn,
    const float* __restrict__ bp, const float* __restrict__ bn,
    float* __restrict__ part)
{
    const int gid = blockIdx.x * 256 + threadIdx.x;
    float m = 0.0f;
    const int n4 = NIN * NOUT / 4;
    const float4* wp4 = (const float4*)wp;
    const float4* wn4 = (const float4*)wn;
    for (int idx = gid; idx < n4; idx += gridDim.x * 256) {
        float4 a = wp4[idx], b = wn4[idx];
        m = fmaxf(m, fmaxf(fmaxf(fabsf(a.x), fabsf(a.y)), fmaxf(fabsf(a.z), fabsf(a.w))));
        m = fmaxf(m, fmaxf(fmaxf(fabsf(b.x), fabsf(b.y)), fmaxf(fabsf(b.z), fabsf(b.w))));
    }
    if (blockIdx.x == 0 && threadIdx.x < NOUT) {
        m = fmaxf(m, fabsf(bp[threadIdx.x]));
        m = fmaxf(m, fabsf(bn[threadIdx.x]));
    }
    #pragma unroll
    for (int off = 1; off < 64; off <<= 1)
        m = fmaxf(m, __shfl_xor(m, off, 64));
    __shared__ float sm[4];
    if ((threadIdx.x & 63) == 0) sm[threadIdx.x >> 6] = m;
    __syncthreads();
    if (threadIdx.x == 0)
        part[blockIdx.x] = fmaxf(fmaxf(sm[0], sm[1]), fmaxf(sm[2], sm[3]));
}

// ---------------------------------------------------------------------------
// Kernel 2: per-(i,j) table {ep, lgGp, en, lgGn}; kG reduced inline.
// Rows i in [NROWS, NPAD) get zeros (pad rows contribute 0 downstream).
// Grid: NPAD*NOUT/256 = 1600 blocks.
// ---------------------------------------------------------------------------
__global__ __launch_bounds__(256) void mk_table(
    const float* __restrict__ wp, const float* __restrict__ wn,
    const float* __restrict__ bp, const float* __restrict__ bn,
    const float* __restrict__ npar, const float* __restrict__ pm,
    float4* __restrict__ tab)
{
    const int tid = threadIdx.x;
    const float kG = G_DIFF_F / load_maxw(pm, tid);
    const int t = blockIdx.x * 256 + tid;
    const int i = t >> 9, jp = t & 511;
    float4 r = make_float4(0.f, 0.f, 0.f, 0.f);
    if (i < NROWS) {
        float wpv, wnv;
        if (i < NIN) { wpv = wp[i * NOUT + jp]; wnv = wn[i * NOUT + jp]; }
        else         { wpv = bp[jp];            wnv = bn[jp]; }
        const float2 nv = *(const float2*)(&npar[i * (2 * NOUT) + 2 * jp]);
        r.x = dlog2(nv.x);                                    // ep
        r.y = dlog2(fmaf(kG, fmaxf(wpv, 0.0f), G_MIN_F));     // lgGp
        r.z = dlog2(nv.y);                                    // en
        r.w = dlog2(fmaf(kG, fmaxf(wnv, 0.0f), G_MIN_F));     // lgGn
    }
    tab[t] = r;
}

// ---------------------------------------------------------------------------
// Kernel 3: main crossbar. Writes per-z partial sums (no atomics, no C).
// Grid (8,8,32); block 256 = 64 col-pairs x 4 batch groups; 8 rows/thread.
// Fixed trip count CHUNK=25 -> clean unroll/software-pipelining.
// ---------------------------------------------------------------------------
__global__ __launch_bounds__(256) void mk_main(
    const float* __restrict__ x, const float4* __restrict__ tab,
    float* __restrict__ part)
{
    const int tx = threadIdx.x & 63;
    const int ty = threadIdx.x >> 6;
    const int jp = blockIdx.x * 64 + tx;
    const int b0 = blockIdx.y * 32;
    const int i0 = blockIdx.z * CHUNK;

    // Stage {log2(2|x|), sign}: ii fastest across lanes -> coalesced x reads.
    __shared__ float2 Ls[CHUNK * LSPAD];
    for (int t = threadIdx.x; t < 32 * 32; t += 256) {
        const int bb = t >> 5, ii = t & 31;
        if (ii < CHUNK) {
            const int i = i0 + ii;
            float L = 0.0f, s = 0.0f;
            if (i < NIN) {
                const float v = x[(b0 + bb) * NIN + i];
                s = (v > 0.0f) ? 1.0f : ((v < 0.0f) ? -1.0f : 0.0f);
                L = dlog2(2.0f * fabsf(v));
            } else if (i == NIN) { L = 1.0f; s = 1.0f; }   // bias input v=1
            Ls[ii * LSPAD + bb] = make_float2(L, s);
        }
    }
    __syncthreads();

    float acc[8];
    #pragma unroll
    for (int b = 0; b < 8; ++b) acc[b] = 0.0f;

    const float4* trow = &tab[i0 * NOUT + jp];
    #pragma unroll 5
    for (int ii = 0; ii < CHUNK; ++ii) {
        const float4 tv = trow[ii * NOUT];        // {ep, lgGp, en, lgGn}
        const float2* lsrow = &Ls[ii * LSPAD + ty * 8];
        #pragma unroll
        for (int b = 0; b < 8; ++b) {
            const float2 ls = lsrow[b];           // wave-broadcast
            const float tp = dexp2(fmaf(tv.x, ls.x, tv.y));
            const float tn = dexp2(fmaf(tv.z, ls.x, tv.w));
            acc[b] = fmaf(ls.y, tp - tn, acc[b]);
        }
    }

    float* pr = &part[(size_t)blockIdx.z * (BATCH * NOUT) + b0 * NOUT + jp];
    #pragma unroll
    for (int b = 0; b < 8; ++b)
        pr[(ty * 8 + b) * NOUT] = acc[b];
}

// ---------------------------------------------------------------------------
// Kernel 4: reduce 32 z-partials per output, scale by C. Grid 512 blocks.
// ---------------------------------------------------------------------------
__global__ __launch_bounds__(256) void mk_reduce(
    const float* __restrict__ part, const float* __restrict__ pm,
    float* __restrict__ out)
{
    const int tid = threadIdx.x;
    const float C = 0.5f * load_maxw(pm, tid) / G_DIFF_F;  // 0.5/kG
    const int g = blockIdx.x * 256 + tid;
    float s = 0.0f;
    #pragma unroll
    for (int z = 0; z < NZ; ++z)
        s += part[(size_t)z * (BATCH * NOUT) + g];
    out[g] = C * s;
}

// ---------------------------------------------------------------------------
// Fallback path (ws too small): kg + zero-out + atomic main (round-5 style).
// ---------------------------------------------------------------------------
__global__ __launch_bounds__(128) void mk_kg(
    const float* __restrict__ part, float* __restrict__ kg)
{
    float m = part[threadIdx.x];
    #pragma unroll
    for (int off = 1; off < 64; off <<= 1)
        m = fmaxf(m, __shfl_xor(m, off, 64));
    __shared__ float sm[2];
    if ((threadIdx.x & 63) == 0) sm[threadIdx.x >> 6] = m;
    __syncthreads();
    if (threadIdx.x == 0) {
        m = fmaxf(sm[0], sm[1]);
        const float kG = G_DIFF_F / m;
        kg[0] = kG;
        kg[1] = 0.5f / kG;
    }
}

__global__ __launch_bounds__(256) void mk_zero(float4* __restrict__ out4)
{
    out4[blockIdx.x * 256 + threadIdx.x] = make_float4(0.f, 0.f, 0.f, 0.f);
}

__global__ __launch_bounds__(256) void mk_main_fb(
    const float* __restrict__ x,  const float* __restrict__ wp,
    const float* __restrict__ wn, const float* __restrict__ bp,
    const float* __restrict__ bn, const float* __restrict__ npar,
    const float* __restrict__ kg, float* __restrict__ out)
{
    const int tx = threadIdx.x & 63;
    const int ty = threadIdx.x >> 6;
    const int jp = blockIdx.x * 64 + tx;
    const int b0 = blockIdx.y * 32;
    const int i0 = blockIdx.z * CHUNK;
    const int iN = min(NROWS - i0, CHUNK);

    __shared__ float2 Ls[CHUNK * LSPAD];
    for (int t = threadIdx.x; t < 32 * 32; t += 256) {
        const int bb = t >> 5, ii = t & 31;
        if (ii < iN) {
            const int i = i0 + ii;
            const float v = (i < NIN) ? x[(b0 + bb) * NIN + i] : 1.0f;
            const float s = (v > 0.0f) ? 1.0f : ((v < 0.0f) ? -1.0f : 0.0f);
            Ls[ii * LSPAD + bb] = make_float2(dlog2(2.0f * fabsf(v)), s);
        }
    }
    __syncthreads();

    const float kG = kg[0];
    float acc[8];
    #pragma unroll
    for (int b = 0; b < 8; ++b) acc[b] = 0.0f;

    for (int ii = 0; ii < iN; ++ii) {
        const int i = i0 + ii;
        float wpv, wnv;
        if (i < NIN) { wpv = wp[i * NOUT + jp]; wnv = wn[i * NOUT + jp]; }
        else         { wpv = bp[jp];            wnv = bn[jp]; }
        const float2 nv = *(const float2*)(&npar[i * (2 * NOUT) + 2 * jp]);
        const float lgGp = dlog2(fmaf(kG, fmaxf(wpv, 0.0f), G_MIN_F));
        const float lgGn = dlog2(fmaf(kG, fmaxf(wnv, 0.0f), G_MIN_F));
        const float ep = dlog2(nv.x);
        const float en = dlog2(nv.y);
        const float2* lsrow = &Ls[ii * LSPAD + ty * 8];
        #pragma unroll
        for (int b = 0; b < 8; ++b) {
            const float2 ls = lsrow[b];
            const float tp = dexp2(fmaf(ep, ls.x, lgGp));
            const float tn = dexp2(fmaf(en, ls.x, lgGn));
            acc[b] = fmaf(ls.y, tp - tn, acc[b]);
        }
    }

    const float C = kg[1];
    #pragma unroll
    for (int b = 0; b < 8; ++b)
        unsafeAtomicAdd(&out[(b0 + ty * 8 + b) * NOUT + jp], C * acc[b]);
}

extern "C" void kernel_launch(void* const* d_in, const int* in_sizes, int n_in,
                              void* d_out, int out_size, void* d_ws, size_t ws_size,
                              hipStream_t stream) {
    const float* x    = (const float*)d_in[0];
    const float* wp   = (const float*)d_in[1];
    const float* wn   = (const float*)d_in[2];
    const float* bp   = (const float*)d_in[3];
    const float* bn   = (const float*)d_in[4];
    const float* npar = (const float*)d_in[5];
    float*        out = (float*)d_out;
    float*         pm = (float*)((char*)d_ws + WS_PM_OFF);

    mk_max<<<128, 256, 0, stream>>>(wp, wn, bp, bn, pm);

    dim3 grid(8, 8, NZ);
    if (ws_size >= WS_TOTAL) {
        float4* tab  = (float4*)((char*)d_ws + WS_TAB_OFF);
        float*  part = (float*)((char*)d_ws + WS_PART_OFF);
        mk_table<<<NPAD * NOUT / 256, 256, 0, stream>>>(wp, wn, bp, bn, npar, pm, tab);
        mk_main<<<grid, 256, 0, stream>>>(x, tab, part);
        mk_reduce<<<BATCH * NOUT / 256, 256, 0, stream>>>(part, pm, out);
    } else {
        float* kg = (float*)((char*)d_ws + WS_KG_OFF);
        mk_kg<<<1, 128, 0, stream>>>(pm, kg);
        mk_zero<<<BATCH * NOUT / 4 / 256, 256, 0, stream>>>((float4*)out);
        mk_main_fb<<<grid, 256, 0, stream>>>(x, wp, wn, bp, bn, npar, kg, out);
    }
}

// Round 7
// 44.045 us; speedup vs baseline: 1.1102x; 1.1102x over previous
//
#include <hip/hip_runtime.h>

#define NIN   784
#define NOUT  512
#define NROWS 785      // NIN + 1 (bias row)
#define NPAD  800      // padded to 32 chunks * 25 (pad rows contribute 0)
#define BATCH 256
#define CHUNK 25
#define LSPAD 33       // 32 batches + 1 pad
#define NZ    32

static constexpr float G_MIN_F  = (float)(1.0 / 983.3);
static constexpr float G_DIFF_F = (float)(1.0 / 281.3 - 1.0 / 983.3);

// device fast transcendental: v_log_f32 (log2), v_exp_f32 (2^x)
__device__ __forceinline__ float dlog2(float v) { return __builtin_amdgcn_logf(v); }
__device__ __forceinline__ float dexp2(float v) { return __builtin_amdgcn_exp2f(v); }

// ws layout:
//   [0]    : 128 float partial maxima
//   [2048] : kG,C (fallback path only)
//   [4096] : table, NPAD*NOUT float4 (6.55 MB)
#define WS_PM_OFF   0
#define WS_KG_OFF   2048
#define WS_TAB_OFF  4096
#define WS_TOTAL    (WS_TAB_OFF + (size_t)NPAD * NOUT * 16)

// 256-thread-block reduce of the 128 partial maxima (all threads return max).
// Contains its own __syncthreads; call before other block syncs diverge.
__device__ __forceinline__ float load_maxw(const float* __restrict__ pm, int tid) {
    float m = pm[tid & 127];
    #pragma unroll
    for (int off = 1; off < 64; off <<= 1)
        m = fmaxf(m, __shfl_xor(m, off, 64));
    __shared__ float sm2[4];
    if ((tid & 63) == 0) sm2[tid >> 6] = m;
    __syncthreads();
    return fmaxf(fmaxf(sm2[0], sm2[1]), fmaxf(sm2[2], sm2[3]));
}

// ---------------------------------------------------------------------------
// Kernel 1: per-block partial max over |weights| (vectorized) + zero d_out.
// 128 blocks x 256 threads; 32768 float4 = exactly one per thread.
// ---------------------------------------------------------------------------
__global__ __launch_bounds__(256) void mk_max(
    const float* __restrict__ wp, const float* __restrict__ wn,
    const float* __restrict__ bp, const float* __restrict__ bn,
    float* __restrict__ part, float4* __restrict__ out4)
{
    const int gid = blockIdx.x * 256 + threadIdx.x;
    out4[gid] = make_float4(0.f, 0.f, 0.f, 0.f);

    float m = 0.0f;
    const int n4 = NIN * NOUT / 4;
    const float4* wp4 = (const float4*)wp;
    const float4* wn4 = (const float4*)wn;
    for (int idx = gid; idx < n4; idx += gridDim.x * 256) {
        float4 a = wp4[idx], b = wn4[idx];
        m = fmaxf(m, fmaxf(fmaxf(fabsf(a.x), fabsf(a.y)), fmaxf(fabsf(a.z), fabsf(a.w))));
        m = fmaxf(m, fmaxf(fmaxf(fabsf(b.x), fabsf(b.y)), fmaxf(fabsf(b.z), fabsf(b.w))));
    }
    if (blockIdx.x == 0 && threadIdx.x < NOUT) {
        m = fmaxf(m, fabsf(bp[threadIdx.x]));
        m = fmaxf(m, fabsf(bn[threadIdx.x]));
    }
    #pragma unroll
    for (int off = 1; off < 64; off <<= 1)
        m = fmaxf(m, __shfl_xor(m, off, 64));
    __shared__ float sm[4];
    if ((threadIdx.x & 63) == 0) sm[threadIdx.x >> 6] = m;
    __syncthreads();
    if (threadIdx.x == 0)
        part[blockIdx.x] = fmaxf(fmaxf(sm[0], sm[1]), fmaxf(sm[2], sm[3]));
}

// ---------------------------------------------------------------------------
// Kernel 2: per-(i,j) table {ep, lgGp, en, lgGn}; maxw reduced inline.
// Rows i in [NROWS, NPAD) get zeros (pad rows contribute 0 downstream).
// ---------------------------------------------------------------------------
__global__ __launch_bounds__(256) void mk_table(
    const float* __restrict__ wp, const float* __restrict__ wn,
    const float* __restrict__ bp, const float* __restrict__ bn,
    const float* __restrict__ npar, const float* __restrict__ pm,
    float4* __restrict__ tab)
{
    const int tid = threadIdx.x;
    const float kG = G_DIFF_F / load_maxw(pm, tid);
    const int t = blockIdx.x * 256 + tid;
    const int i = t >> 9, jp = t & 511;
    float4 r = make_float4(0.f, 0.f, 0.f, 0.f);
    if (i < NROWS) {
        float wpv, wnv;
        if (i < NIN) { wpv = wp[i * NOUT + jp]; wnv = wn[i * NOUT + jp]; }
        else         { wpv = bp[jp];            wnv = bn[jp]; }
        const float2 nv = *(const float2*)(&npar[i * (2 * NOUT) + 2 * jp]);
        r.x = dlog2(nv.x);                                    // ep
        r.y = dlog2(fmaf(kG, fmaxf(wpv, 0.0f), G_MIN_F));     // lgGp
        r.z = dlog2(nv.y);                                    // en
        r.w = dlog2(fmaf(kG, fmaxf(wnv, 0.0f), G_MIN_F));     // lgGn
    }
    tab[t] = r;
}

// ---------------------------------------------------------------------------
// Kernel 3: main crossbar, atomic epilogue.
// y[b,j] = C * sum_i s[b,i] * ( 2^(ep*L + lgGp) - 2^(en*L + lgGn) )
// Grid (8,8,32); block 256 = 64 col-pairs x 4 batch groups; 8 rows/thread.
// Fixed trip count + depth-2 table prefetch pipeline.
// ---------------------------------------------------------------------------
__global__ __launch_bounds__(256) void mk_main(
    const float* __restrict__ x, const float4* __restrict__ tab,
    const float* __restrict__ pm, float* __restrict__ out)
{
    const int tid = threadIdx.x;
    const float C = 0.5f * load_maxw(pm, tid) / G_DIFF_F;   // 0.5/kG

    const int tx = tid & 63;
    const int ty = tid >> 6;
    const int jp = blockIdx.x * 64 + tx;
    const int b0 = blockIdx.y * 32;
    const int i0 = blockIdx.z * CHUNK;

    // Stage {log2(2|x|), sign}: ii fastest across lanes -> coalesced x reads.
    __shared__ float2 Ls[CHUNK * LSPAD];
    for (int t = tid; t < 32 * 32; t += 256) {
        const int bb = t >> 5, ii = t & 31;
        if (ii < CHUNK) {
            const int i = i0 + ii;
            float L = 0.0f, s = 0.0f;
            if (i < NIN) {
                const float v = x[(b0 + bb) * NIN + i];
                s = (v > 0.0f) ? 1.0f : ((v < 0.0f) ? -1.0f : 0.0f);
                L = dlog2(2.0f * fabsf(v));
            } else if (i == NIN) { L = 1.0f; s = 1.0f; }   // bias input v=1
            Ls[ii * LSPAD + bb] = make_float2(L, s);
        }
    }
    __syncthreads();

    float acc[8];
    #pragma unroll
    for (int b = 0; b < 8; ++b) acc[b] = 0.0f;

    const float4* trow = &tab[i0 * NOUT + jp];

    // depth-2 software pipeline on the table load
    float4 t0 = trow[0];
    float4 t1 = trow[NOUT];
    #pragma unroll
    for (int ii = 0; ii < CHUNK; ++ii) {
        const float4 tv = t0;
        t0 = t1;
        if (ii + 2 < CHUNK) t1 = trow[(ii + 2) * NOUT];
        const float2* lsrow = &Ls[ii * LSPAD + ty * 8];
        #pragma unroll
        for (int b = 0; b < 8; ++b) {
            const float2 ls = lsrow[b];           // wave-broadcast
            const float tp = dexp2(fmaf(tv.x, ls.x, tv.y));
            const float tn = dexp2(fmaf(tv.z, ls.x, tv.w));
            acc[b] = fmaf(ls.y, tp - tn, acc[b]);
        }
    }

    #pragma unroll
    for (int b = 0; b < 8; ++b)
        unsafeAtomicAdd(&out[(b0 + ty * 8 + b) * NOUT + jp], C * acc[b]);
}

// ---------------------------------------------------------------------------
// Fallback path (ws too small): kg + zero-out + direct main.
// ---------------------------------------------------------------------------
__global__ __launch_bounds__(128) void mk_kg(
    const float* __restrict__ part, float* __restrict__ kg)
{
    float m = part[threadIdx.x];
    #pragma unroll
    for (int off = 1; off < 64; off <<= 1)
        m = fmaxf(m, __shfl_xor(m, off, 64));
    __shared__ float sm[2];
    if ((threadIdx.x & 63) == 0) sm[threadIdx.x >> 6] = m;
    __syncthreads();
    if (threadIdx.x == 0) {
        m = fmaxf(sm[0], sm[1]);
        const float kG = G_DIFF_F / m;
        kg[0] = kG;
        kg[1] = 0.5f / kG;
    }
}

__global__ __launch_bounds__(256) void mk_main_fb(
    const float* __restrict__ x,  const float* __restrict__ wp,
    const float* __restrict__ wn, const float* __restrict__ bp,
    const float* __restrict__ bn, const float* __restrict__ npar,
    const float* __restrict__ kg, float* __restrict__ out)
{
    const int tx = threadIdx.x & 63;
    const int ty = threadIdx.x >> 6;
    const int jp = blockIdx.x * 64 + tx;
    const int b0 = blockIdx.y * 32;
    const int i0 = blockIdx.z * CHUNK;
    const int iN = min(NROWS - i0, CHUNK);

    __shared__ float2 Ls[CHUNK * LSPAD];
    for (int t = threadIdx.x; t < 32 * 32; t += 256) {
        const int bb = t >> 5, ii = t & 31;
        if (ii < iN) {
            const int i = i0 + ii;
            const float v = (i < NIN) ? x[(b0 + bb) * NIN + i] : 1.0f;
            const float s = (v > 0.0f) ? 1.0f : ((v < 0.0f) ? -1.0f : 0.0f);
            Ls[ii * LSPAD + bb] = make_float2(dlog2(2.0f * fabsf(v)), s);
        }
    }
    __syncthreads();

    const float kG = kg[0];
    float acc[8];
    #pragma unroll
    for (int b = 0; b < 8; ++b) acc[b] = 0.0f;

    for (int ii = 0; ii < iN; ++ii) {
        const int i = i0 + ii;
        float wpv, wnv;
        if (i < NIN) { wpv = wp[i * NOUT + jp]; wnv = wn[i * NOUT + jp]; }
        else         { wpv = bp[jp];            wnv = bn[jp]; }
        const float2 nv = *(const float2*)(&npar[i * (2 * NOUT) + 2 * jp]);
        const float lgGp = dlog2(fmaf(kG, fmaxf(wpv, 0.0f), G_MIN_F));
        const float lgGn = dlog2(fmaf(kG, fmaxf(wnv, 0.0f), G_MIN_F));
        const float ep = dlog2(nv.x);
        const float en = dlog2(nv.y);
        const float2* lsrow = &Ls[ii * LSPAD + ty * 8];
        #pragma unroll
        for (int b = 0; b < 8; ++b) {
            const float2 ls = lsrow[b];
            const float tp = dexp2(fmaf(ep, ls.x, lgGp));
            const float tn = dexp2(fmaf(en, ls.x, lgGn));
            acc[b] = fmaf(ls.y, tp - tn, acc[b]);
        }
    }

    const float C = kg[1];
    #pragma unroll
    for (int b = 0; b < 8; ++b)
        unsafeAtomicAdd(&out[(b0 + ty * 8 + b) * NOUT + jp], C * acc[b]);
}

__global__ __launch_bounds__(256) void mk_zero(float4* __restrict__ out4)
{
    out4[blockIdx.x * 256 + threadIdx.x] = make_float4(0.f, 0.f, 0.f, 0.f);
}

extern "C" void kernel_launch(void* const* d_in, const int* in_sizes, int n_in,
                              void* d_out, int out_size, void* d_ws, size_t ws_size,
                              hipStream_t stream) {
    const float* x    = (const float*)d_in[0];
    const float* wp   = (const float*)d_in[1];
    const float* wn   = (const float*)d_in[2];
    const float* bp   = (const float*)d_in[3];
    const float* bn   = (const float*)d_in[4];
    const float* npar = (const float*)d_in[5];
    float*        out = (float*)d_out;
    float*         pm = (float*)((char*)d_ws + WS_PM_OFF);

    // mk_max zeroes d_out (atomic target) and writes 128 partial maxima
    mk_max<<<128, 256, 0, stream>>>(wp, wn, bp, bn, pm, (float4*)out);

    dim3 grid(8, 8, NZ);
    if (ws_size >= WS_TOTAL) {
        float4* tab = (float4*)((char*)d_ws + WS_TAB_OFF);
        mk_table<<<NPAD * NOUT / 256, 256, 0, stream>>>(wp, wn, bp, bn, npar, pm, tab);
        mk_main<<<grid, 256, 0, stream>>>(x, tab, pm, out);
    } else {
        float* kg = (float*)((char*)d_ws + WS_KG_OFF);
        mk_kg<<<1, 128, 0, stream>>>(pm, kg);
        mk_main_fb<<<grid, 256, 0, stream>>>(x, wp, wn, bp, bn, npar, kg, out);
    }
}

// Round 8
// 38.397 us; speedup vs baseline: 1.2735x; 1.1471x over previous
//
#include <hip/hip_runtime.h>

#define NIN   784
#define NOUT  512
#define NROWS 785      // NIN + 1 (bias row)
#define BATCH 256
#define CHUNK 16       // i-rows per block
#define NZ    50       // 50 * 16 = 800 >= 785 (pad rows contribute 0)

static constexpr float G_MIN_F  = (float)(1.0 / 983.3);
static constexpr float G_DIFF_F = (float)(1.0 / 281.3 - 1.0 / 983.3);

// device fast transcendental: v_log_f32 (log2), v_exp_f32 (2^x)
__device__ __forceinline__ float dlog2(float v) { return __builtin_amdgcn_logf(v); }
__device__ __forceinline__ float dexp2(float v) { return __builtin_amdgcn_exp2f(v); }

// 256-thread-block reduce of the 128 partial maxima (all threads return max).
__device__ __forceinline__ float load_maxw(const float* __restrict__ pm, int tid) {
    float m = pm[tid & 127];
    #pragma unroll
    for (int off = 1; off < 64; off <<= 1)
        m = fmaxf(m, __shfl_xor(m, off, 64));
    __shared__ float sm2[4];
    if ((tid & 63) == 0) sm2[tid >> 6] = m;
    __syncthreads();
    return fmaxf(fmaxf(sm2[0], sm2[1]), fmaxf(sm2[2], sm2[3]));
}

// ---------------------------------------------------------------------------
// Kernel 1: per-block partial max over |weights| (vectorized) + zero d_out.
// 128 blocks x 256 threads; 32768 float4 = exactly one per thread.
// ---------------------------------------------------------------------------
__global__ __launch_bounds__(256) void mk_max(
    const float* __restrict__ wp, const float* __restrict__ wn,
    const float* __restrict__ bp, const float* __restrict__ bn,
    float* __restrict__ part, float4* __restrict__ out4)
{
    const int gid = blockIdx.x * 256 + threadIdx.x;
    out4[gid] = make_float4(0.f, 0.f, 0.f, 0.f);

    float m = 0.0f;
    const int n4 = NIN * NOUT / 4;
    const float4* wp4 = (const float4*)wp;
    const float4* wn4 = (const float4*)wn;
    for (int idx = gid; idx < n4; idx += gridDim.x * 256) {
        float4 a = wp4[idx], b = wn4[idx];
        m = fmaxf(m, fmaxf(fmaxf(fabsf(a.x), fabsf(a.y)), fmaxf(fabsf(a.z), fabsf(a.w))));
        m = fmaxf(m, fmaxf(fmaxf(fabsf(b.x), fabsf(b.y)), fmaxf(fabsf(b.z), fabsf(b.w))));
    }
    if (blockIdx.x == 0 && threadIdx.x < NOUT) {
        m = fmaxf(m, fabsf(bp[threadIdx.x]));
        m = fmaxf(m, fabsf(bn[threadIdx.x]));
    }
    #pragma unroll
    for (int off = 1; off < 64; off <<= 1)
        m = fmaxf(m, __shfl_xor(m, off, 64));
    __shared__ float sm[4];
    if ((threadIdx.x & 63) == 0) sm[threadIdx.x >> 6] = m;
    __syncthreads();
    if (threadIdx.x == 0)
        part[blockIdx.x] = fmaxf(fmaxf(sm[0], sm[1]), fmaxf(sm[2], sm[3]));
}

// ---------------------------------------------------------------------------
// Kernel 2: fused table+crossbar. Inner loop touches LDS ONLY.
// y[b,j] = C * sum_i s[b,i] * ( 2^(ep*L + lgGp) - 2^(en*L + lgGn) )
// Grid (8 jtiles, 8 bgroups, 50 ichunks) = 3200 blocks, 256 threads.
// Staging: each block builds its CHUNKx64 float4 table slice in LDS
// (4 pairs/thread, 4 log2 each) and the CHUNKx32 {L,s} slice.
// LDS = 16KB (table) + 4.2KB (Ls) -> 7 blocks/CU, ~87% occupancy.
// ---------------------------------------------------------------------------
__global__ __launch_bounds__(256) void mk_main(
    const float* __restrict__ x,  const float* __restrict__ wp,
    const float* __restrict__ wn, const float* __restrict__ bp,
    const float* __restrict__ bn, const float* __restrict__ npar,
    const float* __restrict__ pm, float* __restrict__ out)
{
    const int tid = threadIdx.x;
    const float maxw = load_maxw(pm, tid);
    const float kG = G_DIFF_F / maxw;
    const float C  = 0.5f * maxw / G_DIFF_F;    // 0.5/kG

    const int tx = tid & 63;
    const int ty = tid >> 6;
    const int j0 = blockIdx.x * 64;
    const int jp = j0 + tx;
    const int b0 = blockIdx.y * 32;
    const int i0 = blockIdx.z * CHUNK;

    __shared__ float4 Tb[CHUNK * 64];           // {ep, lgGp, en, lgGn}
    __shared__ float2 Ls[CHUNK][33];            // {L, s}, +1 pad

    // --- stage table slice: 1024 (ii,jj) pairs, 4 per thread, coalesced ---
    #pragma unroll
    for (int k = 0; k < 4; ++k) {
        const int p  = tid + k * 256;
        const int ii = p >> 6, jj = p & 63;
        const int i  = i0 + ii;
        float4 r = make_float4(0.f, 0.f, 0.f, 0.f);
        if (i < NROWS) {
            const float wpv = (i < NIN) ? wp[i * NOUT + j0 + jj] : bp[j0 + jj];
            const float wnv = (i < NIN) ? wn[i * NOUT + j0 + jj] : bn[j0 + jj];
            const float2 nv = *(const float2*)(&npar[i * (2 * NOUT) + 2 * (j0 + jj)]);
            r.x = dlog2(nv.x);                                  // ep
            r.y = dlog2(fmaf(kG, fmaxf(wpv, 0.0f), G_MIN_F));   // lgGp
            r.z = dlog2(nv.y);                                  // en
            r.w = dlog2(fmaf(kG, fmaxf(wnv, 0.0f), G_MIN_F));   // lgGn
        }
        Tb[p] = r;
    }

    // --- stage {log2(2|x|), sign}: 512 entries, 2 per thread ---
    #pragma unroll
    for (int k = 0; k < 2; ++k) {
        const int t  = tid + k * 256;
        const int bb = t >> 4, ii = t & 15;
        const int i  = i0 + ii;
        float L = 0.0f, s = 0.0f;
        if (i < NIN) {
            const float v = x[(b0 + bb) * NIN + i];
            s = (v > 0.0f) ? 1.0f : ((v < 0.0f) ? -1.0f : 0.0f);
            L = dlog2(2.0f * fabsf(v));
        } else if (i == NIN) { L = 1.0f; s = 1.0f; }   // bias input v=1
        Ls[ii][bb] = make_float2(L, s);
    }
    __syncthreads();

    float acc[8];
    #pragma unroll
    for (int b = 0; b < 8; ++b) acc[b] = 0.0f;

    // --- inner loop: LDS-only, fully unrolled ---
    #pragma unroll
    for (int ii = 0; ii < CHUNK; ++ii) {
        const float4 tv = Tb[ii * 64 + tx];     // per-lane b128, ~12cy pattern
        #pragma unroll
        for (int b = 0; b < 8; ++b) {
            const float2 ls = Ls[ii][ty * 8 + b];   // wave-uniform broadcast
            const float tp = dexp2(fmaf(tv.x, ls.x, tv.y));
            const float tn = dexp2(fmaf(tv.z, ls.x, tv.w));
            acc[b] = fmaf(ls.y, tp - tn, acc[b]);
        }
    }

    #pragma unroll
    for (int b = 0; b < 8; ++b)
        unsafeAtomicAdd(&out[(b0 + ty * 8 + b) * NOUT + jp], C * acc[b]);
}

extern "C" void kernel_launch(void* const* d_in, const int* in_sizes, int n_in,
                              void* d_out, int out_size, void* d_ws, size_t ws_size,
                              hipStream_t stream) {
    const float* x    = (const float*)d_in[0];
    const float* wp   = (const float*)d_in[1];
    const float* wn   = (const float*)d_in[2];
    const float* bp   = (const float*)d_in[3];
    const float* bn   = (const float*)d_in[4];
    const float* npar = (const float*)d_in[5];
    float*        out = (float*)d_out;
    float*         pm = (float*)d_ws;           // 128 partial maxima

    // mk_max zeroes d_out (atomic target) and writes 128 partial maxima
    mk_max<<<128, 256, 0, stream>>>(wp, wn, bp, bn, pm, (float4*)out);

    dim3 grid(NOUT / 64, BATCH / 32, NZ);
    mk_main<<<grid, 256, 0, stream>>>(x, wp, wn, bp, bn, npar, pm, out);
}